// Round 8
// baseline (736.450 us; speedup 1.0000x reference)
//
#include <hip/hip_runtime.h>
#include <hip/hip_bf16.h>
#include <cmath>

#define NN 100000
#define NE 800000
#define ETOT (NE + NN)
#define MP 100096            // 782 * 128, padded row count

#define SCHUNK 512
#define NBLK ((NN + SCHUNK - 1) / SCHUNK)   // 196

typedef __attribute__((ext_vector_type(8))) short bf16x8;
typedef __attribute__((ext_vector_type(4))) float f32x4;

__device__ inline void gl_lds16(const void* g, void* l) {
    __builtin_amdgcn_global_load_lds(
        (const __attribute__((address_space(1))) void*)g,
        (__attribute__((address_space(3))) void*)l, 16, 0, 0);
}

__device__ inline ushort f2bf(float f) {
    __hip_bfloat16 b = __float2bfloat16(f);
    return *(ushort*)&b;
}
__device__ inline uint pk2(float a, float b) {
    return (uint)f2bf(a) | ((uint)f2bf(b) << 16);
}

// ---------------- panel GEMM: C[M,N] = A[M,Kp] @ Bt[N,Kp]^T -----------------
// Shaped for tall-skinny: block = 128 rows x 128 cols; whole 128-col B panel
// staged in LDS per 128-K phase (<=3 phases); A goes global->VGPR directly
// (rows are wave-private). 4 waves, each 32 rows x 128 cols = 2x8 MFMA tiles.
// Barriers: one pair per phase (vs per-32-K) -> 256 MFMA/wave per barrier.
// flags: 1 = relu, 2 = bf16 output (else fp32), 4 = accumulate BN stats
// Optional fused row-dot: dotout[row] += sum_col v[row,col]*dotv[col]
__global__ __launch_bounds__(256)
void gemm_panel(const __hip_bfloat16* __restrict__ Abf,
                const __hip_bfloat16* __restrict__ Btbf,
                const float* __restrict__ bias, void* __restrict__ out,
                const float* __restrict__ dotv, float* __restrict__ dotout,
                float* __restrict__ stats,
                int Kp, int ldc, int Mstore, int Nstore, int flags)
{
    __shared__ __align__(16) short Bs[128 * 128];   // 32 KB
    const short* A  = (const short*)Abf;
    const short* Bt = (const short*)Btbf;

    const int tid  = threadIdx.x;
    const int lane = tid & 63;
    const int wv   = tid >> 6;
    const int quad = lane >> 4;
    const int l16  = lane & 15;
    const long bm = (long)blockIdx.x * 128;
    const long bn = (long)blockIdx.y * 128;

    f32x4 acc[2][8] = {};

    const short* a_row0 = A + (bm + wv * 32 + l16) * (long)Kp;
    const short* a_row1 = a_row0 + 16 * (long)Kp;

    for (int k0 = 0; k0 < Kp; k0 += 128) {
        const int nc   = min(16, (Kp - k0) >> 3);   // 16B chunks per B row (16 or 8)
        const int mask = nc - 1;
        const int sh   = (nc == 16) ? 4 : 3;

        if (k0 > 0) __syncthreads();                // protect LDS reuse
        const int slots = 128 * nc;
        for (int i = 0; i < slots; i += 256) {
            int s = i + tid;
            int row = s >> sh;
            int cslot = s & mask;
            int gc = cslot ^ (row & mask);          // XOR swizzle (2-way max = free)
            gl_lds16(Bt + (bn + row) * (long)Kp + k0 + gc * 8, &Bs[s * 8]);
        }
        __syncthreads();                            // staging drain (once per phase)

        const int nkk = nc >> 2;                    // 32-K steps this phase
        const int cxor = l16 & mask;
#pragma unroll 4
        for (int kk = 0; kk < nkk; kk++) {
            bf16x8 a0 = *(const bf16x8*)(a_row0 + k0 + kk * 32 + quad * 8);
            bf16x8 a1 = *(const bf16x8*)(a_row1 + k0 + kk * 32 + quad * 8);
            const int cs = (kk * 4 + quad) ^ cxor;
#pragma unroll
            for (int j = 0; j < 8; j++) {
                bf16x8 bfj = *(const bf16x8*)&Bs[(j * 16 + l16) * (nc * 8) + cs * 8];
                acc[0][j] = __builtin_amdgcn_mfma_f32_16x16x32_bf16(a0, bfj, acc[0][j], 0, 0, 0);
                acc[1][j] = __builtin_amdgcn_mfma_f32_16x16x32_bf16(a1, bfj, acc[1][j], 0, 0, 0);
            }
        }
    }

    __hip_bfloat16* outb = (__hip_bfloat16*)out;
    float* outf = (float*)out;
    float dp[8];
    float sv[8], sv2[8];
#pragma unroll
    for (int t = 0; t < 8; t++) { dp[t] = 0.f; sv[t] = 0.f; sv2[t] = 0.f; }

#pragma unroll
    for (int rt = 0; rt < 2; rt++) {
        long row_base = bm + wv * 32 + rt * 16 + quad * 4;
#pragma unroll
        for (int j = 0; j < 8; j++) {
            long col = bn + j * 16 + l16;
            if (col >= Nstore) continue;
            float bv = bias ? bias[col] : 0.f;
            float dv = dotout ? dotv[col] : 0.f;
#pragma unroll
            for (int r = 0; r < 4; r++) {
                long row = row_base + r;
                float v = acc[rt][j][r] + bv;
                if (flags & 1) v = fmaxf(v, 0.f);
                dp[rt * 4 + r] = fmaf(v, dv, dp[rt * 4 + r]);
                if (row >= Mstore) continue;
                if (flags & 4) { sv[j] += v; sv2[j] += v * v; }
                if (flags & 2) outb[row * ldc + col] = __float2bfloat16(v);
                else           outf[row * ldc + col] = v;
            }
        }
    }

    if (dotout) {
#pragma unroll
        for (int t = 0; t < 8; t++) {
            float s = dp[t];
            s += __shfl_xor(s, 1); s += __shfl_xor(s, 2);
            s += __shfl_xor(s, 4); s += __shfl_xor(s, 8);
            if (l16 == 0) {
                long row = bm + wv * 32 + (t >> 2) * 16 + quad * 4 + (t & 3);
                if (row < Mstore) atomicAdd(&dotout[row], s);
            }
        }
    }

    if (flags & 4) {
#pragma unroll
        for (int j = 0; j < 8; j++) {
            long col = bn + j * 16 + l16;
            if (col >= Nstore) continue;
            float s = sv[j], s2 = sv2[j];
            s  += __shfl_xor(s, 16);  s  += __shfl_xor(s, 32);
            s2 += __shfl_xor(s2, 16); s2 += __shfl_xor(s2, 32);
            if (quad == 0) {
                atomicAdd(&stats[col], s);
                atomicAdd(&stats[64 + col], s2);
            }
        }
    }
}

// ---------------- casts ----------------
// x [NN,300] fp32 -> [MP,320] bf16 zero-padded. 8 cols/thread, 40 thr/row.
__global__ __launch_bounds__(256)
void cast_x_vec(const float* __restrict__ x, __hip_bfloat16* __restrict__ xb)
{
    const int idx = blockIdx.x * 256 + threadIdx.x;
    if (idx >= MP * 40) return;
    const int row = idx / 40;
    const int c8  = (idx % 40) * 8;
    uint4 v;
    if (row < NN && c8 + 8 <= 300) {
        const float* xp = x + (size_t)row * 300 + c8;
        float4 f0 = *(const float4*)xp;
        float4 f1 = *(const float4*)(xp + 4);
        v.x = pk2(f0.x, f0.y); v.y = pk2(f0.z, f0.w);
        v.z = pk2(f1.x, f1.y); v.w = pk2(f1.z, f1.w);
    } else {
        float f[8];
#pragma unroll
        for (int k = 0; k < 8; k++)
            f[k] = (row < NN && c8 + k < 300) ? x[(size_t)row * 300 + c8 + k] : 0.f;
        v.x = pk2(f[0], f[1]); v.y = pk2(f[2], f[3]);
        v.z = pk2(f[4], f[5]); v.w = pk2(f[6], f[7]);
    }
    *(uint4*)((ushort*)xb + (size_t)row * 320 + c8) = v;
}

// merged small-tensor prep: 4 transposed weight casts + 2 attention matvecs
__device__ inline void castT_one(const float* __restrict__ w,
                                 __hip_bfloat16* __restrict__ wt,
                                 int K, int N, int Kp, int idx)
{
    int n = idx / Kp, k = idx % Kp;
    float v = (n < N && k < K) ? w[(size_t)k * N + n] : 0.f;
    wt[idx] = __float2bfloat16(v);
}

__global__ __launch_bounds__(256)
void prep_small(const float* __restrict__ lin_w, const float* __restrict__ w1_src,
                const float* __restrict__ w2_src, const float* __restrict__ fc1_w,
                const float* __restrict__ w1_dst, const float* __restrict__ a1_dst,
                const float* __restrict__ w2_dst, const float* __restrict__ a2_dst,
                __hip_bfloat16* __restrict__ wlinT, __hip_bfloat16* __restrict__ w1T,
                __hip_bfloat16* __restrict__ w2T, __hip_bfloat16* __restrict__ fc1T,
                float* __restrict__ vvec1, float* __restrict__ vvec2)
{
    const int b = blockIdx.x;
    const int tid = threadIdx.x;
    if (b < 320) {                       // wlinT: 256x320
        castT_one(lin_w, wlinT, 300, 256, 320, b * 256 + tid);
    } else if (b < 576) {                // w1T: 256x256
        castT_one(w1_src, w1T, 256, 256, 256, (b - 320) * 256 + tid);
    } else if (b < 704) {                // w2T: 128x256
        castT_one(w2_src, w2T, 256, 128, 256, (b - 576) * 256 + tid);
    } else if (b < 768) {                // fc1T: 128x128 (N=64 real)
        castT_one(fc1_w, fc1T, 128, 64, 128, (b - 704) * 256 + tid);
    } else if (b == 768) {               // vvec1[i] = sum_j w1_dst[i,j]*a1_dst[j]
        float s = 0.f;
        for (int j = 0; j < 256; j++) s = fmaf(w1_dst[(size_t)tid * 256 + j], a1_dst[j], s);
        vvec1[tid] = s;
    } else {                             // vvec2[i] = sum_j w2_dst[i,j]*a2_dst[j]
        float s = 0.f;
        for (int j = 0; j < 128; j++) s = fmaf(w2_dst[(size_t)tid * 128 + j], a2_dst[j], s);
        vvec2[tid] = s;
    }
}

// ---------------- CSR build ----------------
__global__ void count_edges(const int* __restrict__ ei, int* __restrict__ counts)
{
    int e = blockIdx.x * blockDim.x + threadIdx.x;
    if (e >= ETOT) return;
    int d = (e < NE) ? ei[NE + e] : (e - NE);
    atomicAdd(&counts[d], 1);
}

__global__ __launch_bounds__(256)
void scan_partial(const int* __restrict__ counts, int* __restrict__ blk)
{
    __shared__ int sh[256];
    const int tid = threadIdx.x;
    const int base = blockIdx.x * SCHUNK + tid * 2;
    int c0 = (base < NN)     ? counts[base]     : 0;
    int c1 = (base + 1 < NN) ? counts[base + 1] : 0;
    sh[tid] = c0 + c1;
    __syncthreads();
    for (int off = 128; off; off >>= 1) {
        if (tid < off) sh[tid] += sh[tid + off];
        __syncthreads();
    }
    if (tid == 0) blk[blockIdx.x] = sh[0];
}

__global__ __launch_bounds__(256)
void scan_blocks(int* __restrict__ blk)
{
    __shared__ int sh[256];
    const int tid = threadIdx.x;
    int v = (tid < NBLK) ? blk[tid] : 0;
    sh[tid] = v;
    __syncthreads();
    for (int off = 1; off < 256; off <<= 1) {
        int u = (tid >= off) ? sh[tid - off] : 0;
        __syncthreads();
        sh[tid] += u;
        __syncthreads();
    }
    if (tid < NBLK) blk[tid] = sh[tid] - v;   // exclusive
}

__global__ __launch_bounds__(256)
void scan_fill(const int* __restrict__ counts, const int* __restrict__ blk,
               int* __restrict__ row_ptr, int* __restrict__ cursor)
{
    __shared__ int sh[256];
    const int tid = threadIdx.x;
    const int i0 = blockIdx.x * SCHUNK + tid * 2;
    int c0 = (i0 < NN)     ? counts[i0]     : 0;
    int c1 = (i0 + 1 < NN) ? counts[i0 + 1] : 0;
    int s = c0 + c1;
    sh[tid] = s;
    __syncthreads();
    for (int off = 1; off < 256; off <<= 1) {
        int u = (tid >= off) ? sh[tid - off] : 0;
        __syncthreads();
        sh[tid] += u;
        __syncthreads();
    }
    int pre = sh[tid] - s + blk[blockIdx.x];
    if (i0 < NN)     { row_ptr[i0] = pre;          cursor[i0] = pre; }
    if (i0 + 1 < NN) { row_ptr[i0 + 1] = pre + c0; cursor[i0 + 1] = pre + c0; }
    if (blockIdx.x == 0 && tid == 0) row_ptr[NN] = ETOT;
}

__global__ void fill_edges(const int* __restrict__ ei, int* __restrict__ cursor,
                           int* __restrict__ csr_src)
{
    int e = blockIdx.x * blockDim.x + threadIdx.x;
    if (e >= ETOT) return;
    int s, d;
    if (e < NE) { s = ei[e]; d = ei[NE + e]; }
    else        { s = e - NE; d = s; }
    int pos = atomicAdd(&cursor[d], 1);
    csr_src[pos] = s;
}

// ---------------- GAT attention + aggregation ------------------------------
// LPN lanes per node, 4 channels per lane (C = LPN*4). Softmax WITHOUT max
// subtraction (shift-invariant; e = a_s + a_d is O(1) here). (w,src) staged
// in per-wave LDS; 8 gathers in flight per iter.
template<int LPN>
__global__ __launch_bounds__(256)
void gat_agg_wave(const __hip_bfloat16* __restrict__ hsrc,
                  const float* __restrict__ a_s,
                  const float* __restrict__ a_d,
                  const int* __restrict__ row_ptr,
                  const int* __restrict__ csr_src,
                  const float* __restrict__ bias,
                  __hip_bfloat16* __restrict__ outh,
                  const float* __restrict__ dotv,
                  float* __restrict__ dotout)
{
    const int C = LPN * 4;
    const int NPB = 256 / LPN;               // nodes per block
    __shared__ __align__(16) float2 ws_sh[NPB][LPN];

    const int tid  = threadIdx.x;
    const int slot = tid / LPN;
    const int sub  = tid % LPN;
    const int n = blockIdx.x * NPB + slot;
    if (n >= NN) return;

    const int start = row_ptr[n];
    const int deg = row_ptr[n + 1] - start;
    const float a_dn = a_d[n];
    const ushort* hp = (const ushort*)hsrc;

    float S = 0.f;
    float acc0 = 0.f, acc1 = 0.f, acc2 = 0.f, acc3 = 0.f;

    for (int c0 = 0; c0 < deg; c0 += LPN) {
        const int cnt = min(LPN, deg - c0);
        int sj = 0; float w = 0.f;
        if (sub < cnt) {
            sj = csr_src[start + c0 + sub];
            float t = a_s[sj] + a_dn;
            t = (t >= 0.f) ? t : 0.2f * t;
            w = __expf(t);
        }
        S += w;
        ws_sh[slot][sub] = make_float2(w, __int_as_float(sj));

        const int cnt8 = (cnt + 7) & ~7;
        const ushort* hpl = hp + sub * 4;
        for (int j = 0; j < cnt8; j += 8) {
            float4 p0 = *(const float4*)&ws_sh[slot][j];
            float4 p1 = *(const float4*)&ws_sh[slot][j + 2];
            float4 p2 = *(const float4*)&ws_sh[slot][j + 4];
            float4 p3 = *(const float4*)&ws_sh[slot][j + 6];
            uint2 u0 = *(const uint2*)(hpl + (size_t)__float_as_int(p0.y) * C);
            uint2 u1 = *(const uint2*)(hpl + (size_t)__float_as_int(p0.w) * C);
            uint2 u2 = *(const uint2*)(hpl + (size_t)__float_as_int(p1.y) * C);
            uint2 u3 = *(const uint2*)(hpl + (size_t)__float_as_int(p1.w) * C);
            uint2 u4 = *(const uint2*)(hpl + (size_t)__float_as_int(p2.y) * C);
            uint2 u5 = *(const uint2*)(hpl + (size_t)__float_as_int(p2.w) * C);
            uint2 u6 = *(const uint2*)(hpl + (size_t)__float_as_int(p3.y) * C);
            uint2 u7 = *(const uint2*)(hpl + (size_t)__float_as_int(p3.w) * C);
#define ACC4(W, U) \
            acc0 = fmaf(W, __uint_as_float(U.x << 16), acc0); \
            acc1 = fmaf(W, __uint_as_float(U.x & 0xffff0000u), acc1); \
            acc2 = fmaf(W, __uint_as_float(U.y << 16), acc2); \
            acc3 = fmaf(W, __uint_as_float(U.y & 0xffff0000u), acc3);
            ACC4(p0.x, u0) ACC4(p0.z, u1) ACC4(p1.x, u2) ACC4(p1.z, u3)
            ACC4(p2.x, u4) ACC4(p2.z, u5) ACC4(p3.x, u6) ACC4(p3.z, u7)
#undef ACC4
        }
    }

#pragma unroll
    for (int off = LPN / 2; off; off >>= 1) S += __shfl_xor(S, off);

    float inv = 1.f / (S + 1e-16f);
    const float4 b4 = *(const float4*)&bias[sub * 4];
    float o0 = fmaxf(acc0 * inv + b4.x, 0.f);
    float o1 = fmaxf(acc1 * inv + b4.y, 0.f);
    float o2 = fmaxf(acc2 * inv + b4.z, 0.f);
    float o3 = fmaxf(acc3 * inv + b4.w, 0.f);

    ushort4 v;
    v.x = f2bf(o0); v.y = f2bf(o1); v.z = f2bf(o2); v.w = f2bf(o3);
    *(ushort4*)((ushort*)outh + (size_t)n * C + sub * 4) = v;

    if (dotout) {
        const float4 d4 = *(const float4*)&dotv[sub * 4];
        float dp = o0 * d4.x + o1 * d4.y + o2 * d4.z + o3 * d4.w;
#pragma unroll
        for (int off = LPN / 2; off; off >>= 1) dp += __shfl_xor(dp, off);
        if (sub == 0) dotout[n] = dp;
    }
}

// ---------------- BN finalize + fused head ----------------
__global__ void bn_finalize(const float* __restrict__ stats,
                            const float* __restrict__ g, const float* __restrict__ b,
                            float* __restrict__ ss)
{
    int c = threadIdx.x;
    float mu = stats[c] / (float)NN;
    float var = stats[64 + c] / (float)NN - mu * mu;
    float rs = rsqrtf(var + 1e-5f);
    float sc = rs * g[c];
    ss[c] = sc;
    ss[64 + c] = b[c] - mu * sc;
}

__global__ __launch_bounds__(256)
void final_head(const float* __restrict__ h3, const float* __restrict__ ss,
                const float* __restrict__ fc2_w, const float* __restrict__ fc2_b,
                float* __restrict__ out)
{
    int lane = threadIdx.x & 63;
    int n = blockIdx.x * 4 + (threadIdx.x >> 6);
    if (n >= NN) return;
    float y = h3[(size_t)n * 64 + lane];
    y = fmaxf(y * ss[lane] + ss[64 + lane], 0.f);
    float z[4];
#pragma unroll
    for (int o = 0; o < 4; o++) {
        float p = y * fc2_w[lane * 4 + o];
#pragma unroll
        for (int off = 32; off; off >>= 1) p += __shfl_xor(p, off);
        z[o] = p + fc2_b[o];
    }
    float mx = fmaxf(fmaxf(z[0], z[1]), fmaxf(z[2], z[3]));
    float lse = mx + logf(expf(z[0] - mx) + expf(z[1] - mx) +
                          expf(z[2] - mx) + expf(z[3] - mx));
    if (lane < 4) out[(size_t)n * 4 + lane] = z[lane] - lse;
}

// ---------------- launch ----------------
extern "C" void kernel_launch(void* const* d_in, const int* in_sizes, int n_in,
                              void* d_out, int out_size, void* d_ws, size_t ws_size,
                              hipStream_t stream)
{
    const float* x      = (const float*)d_in[0];
    const int*   ei     = (const int*)d_in[1];
    const float* lin_w  = (const float*)d_in[2];
    const float* lin_b  = (const float*)d_in[3];
    const float* w1_src = (const float*)d_in[4];
    const float* w1_dst = (const float*)d_in[5];
    const float* a1_src = (const float*)d_in[6];
    const float* a1_dst = (const float*)d_in[7];
    const float* b1     = (const float*)d_in[8];
    const float* w2_src = (const float*)d_in[9];
    const float* w2_dst = (const float*)d_in[10];
    const float* a2_src = (const float*)d_in[11];
    const float* a2_dst = (const float*)d_in[12];
    const float* b2     = (const float*)d_in[13];
    const float* fc1_w  = (const float*)d_in[14];
    const float* fc1_b  = (const float*)d_in[15];
    const float* bn_g   = (const float*)d_in[16];
    const float* bn_b   = (const float*)d_in[17];
    const float* fc2_w  = (const float*)d_in[18];
    const float* fc2_b  = (const float*)d_in[19];
    float* out = (float*)d_out;

    // -------- workspace layout (region reuse) --------
    char* p = (char*)d_ws;
    auto alloc = [&](size_t bytes) { char* r = p; p += (bytes + 255) & ~(size_t)255; return r; };
    char* R1 = alloc((size_t)MP * 320 * 2);   // x_bf  -> hsrc1
    char* R2 = alloc((size_t)MP * 256 * 2);   // h0    -> hsrc2 | h2
    char* R3 = alloc((size_t)MP * 256 * 2);   // h1    -> h3(f32)
    __hip_bfloat16* wlinT = (__hip_bfloat16*)alloc(256 * 320 * 2);
    __hip_bfloat16* w1T   = (__hip_bfloat16*)alloc(256 * 256 * 2);
    __hip_bfloat16* w2T   = (__hip_bfloat16*)alloc(128 * 256 * 2);
    __hip_bfloat16* fc1T  = (__hip_bfloat16*)alloc(128 * 128 * 2);
    float* avec  = (float*)alloc((size_t)NN * 4 * 4 + 512); // aS1|aD1|aS2|aD2|stats
    float* aS1 = avec;
    float* aD1 = avec + NN;
    float* aS2 = avec + 2 * (size_t)NN;
    float* aD2 = avec + 3 * (size_t)NN;
    float* stats = avec + 4 * (size_t)NN;     // 128 floats, zeroed with avec
    float* vvec1 = (float*)alloc(256 * 4);
    float* vvec2 = (float*)alloc(256 * 4);
    float* ss    = (float*)alloc(128 * 4);
    int* row_ptr = (int*)alloc((size_t)(NN + 1) * 4);
    int* cursor  = (int*)alloc((size_t)(NN + 1) * 4);
    int* counts  = (int*)alloc((size_t)NN * 4);
    int* blk     = (int*)alloc(256 * 4);
    int* csr_src = (int*)alloc((size_t)ETOT * 4);

    __hip_bfloat16* x_bf  = (__hip_bfloat16*)R1;
    __hip_bfloat16* hsrc1 = (__hip_bfloat16*)R1;
    __hip_bfloat16* h0    = (__hip_bfloat16*)R2;
    __hip_bfloat16* hsrc2 = (__hip_bfloat16*)R2;
    __hip_bfloat16* h2    = (__hip_bfloat16*)(R2 + (size_t)MP * 128 * 2);
    __hip_bfloat16* h1    = (__hip_bfloat16*)R3;
    float*          h3    = (float*)R3;

    const int eb = (ETOT + 255) / 256;
    const int MB = MP / 128;   // 782

    // zero atomic dot outputs + BN stats in one memset
    hipMemsetAsync(avec, 0, sizeof(float) * NN * 4 + 512, stream);

    // CSR build (parallel 3-phase scan; reused by both GAT layers)
    hipMemsetAsync(counts, 0, sizeof(int) * NN, stream);
    count_edges<<<eb, 256, 0, stream>>>(ei, counts);
    scan_partial<<<NBLK, 256, 0, stream>>>(counts, blk);
    scan_blocks<<<1, 256, 0, stream>>>(blk);
    scan_fill<<<NBLK, 256, 0, stream>>>(counts, blk, row_ptr, cursor);
    fill_edges<<<eb, 256, 0, stream>>>(ei, cursor, csr_src);

    // casts + attention weight matvecs (merged)
    cast_x_vec<<<(MP * 40 + 255) / 256, 256, 0, stream>>>(x, x_bf);
    prep_small<<<770, 256, 0, stream>>>(lin_w, w1_src, w2_src, fc1_w,
                                        w1_dst, a1_dst, w2_dst, a2_dst,
                                        wlinT, w1T, w2T, fc1T, vvec1, vvec2);

    // h0 = relu(x @ lin_w + lin_b)   [bf16 out]; fused: aD1 = h0 @ vvec1
    gemm_panel<<<dim3(MB, 2), 256, 0, stream>>>(x_bf, wlinT, lin_b, h0,
                                                vvec1, aD1, nullptr, 320, 256, NN, 256, 3);

    // ---- GAT layer 1 (256 -> 256) ----
    gemm_panel<<<dim3(MB, 2), 256, 0, stream>>>(h0, w1T, nullptr, hsrc1,
                                                a1_src, aS1, nullptr, 256, 256, NN, 256, 2);
    gat_agg_wave<64><<<(NN + 3) / 4, 256, 0, stream>>>(hsrc1, aS1, aD1, row_ptr,
                                                       csr_src, b1, h1, vvec2, aD2);

    // ---- GAT layer 2 (256 -> 128) ----
    gemm_panel<<<dim3(MB, 1), 256, 0, stream>>>(h1, w2T, nullptr, hsrc2,
                                                a2_src, aS2, nullptr, 256, 128, NN, 128, 2);
    gat_agg_wave<32><<<(NN + 7) / 8, 256, 0, stream>>>(hsrc2, aS2, aD2, row_ptr,
                                                       csr_src, b2, h2, nullptr, nullptr);

    // ---- fc1 (+fused BN stats) + BN + relu + fc2 + log_softmax ----
    gemm_panel<<<dim3(MB, 1), 256, 0, stream>>>(h2, fc1T, fc1_b, h3,
                                                nullptr, nullptr, stats, 128, 64, NN, 64, 4);
    bn_finalize<<<1, 64, 0, stream>>>(stats, bn_g, bn_b, ss);
    final_head<<<(NN + 3) / 4, 256, 0, stream>>>(h3, ss, fc2_w, fc2_b, out);
}

// Round 9
// 698.773 us; speedup vs baseline: 1.0539x; 1.0539x over previous
//
#include <hip/hip_runtime.h>
#include <hip/hip_bf16.h>
#include <cmath>

#define NN 100000
#define NE 800000
#define ETOT (NE + NN)
#define MP 100096            // 782 * 128, padded row count

#define SCHUNK 512
#define NBLK ((NN + SCHUNK - 1) / SCHUNK)   // 196

typedef __attribute__((ext_vector_type(8))) short bf16x8;
typedef __attribute__((ext_vector_type(4))) float f32x4;

__device__ inline void gl_lds16(const void* g, void* l) {
    __builtin_amdgcn_global_load_lds(
        (const __attribute__((address_space(1))) void*)g,
        (__attribute__((address_space(3))) void*)l, 16, 0, 0);
}

__device__ inline ushort f2bf(float f) {
    __hip_bfloat16 b = __float2bfloat16(f);
    return *(ushort*)&b;
}
__device__ inline uint pk2(float a, float b) {
    return (uint)f2bf(a) | ((uint)f2bf(b) << 16);
}

// ---------------- MFMA GEMM: C[M,N] = A[M,Kp] @ Bt[N,Kp]^T ------------------
// 128x128 tile, 4 waves, each wave 64x64 = 4x4 MFMA tiles of 16x16x32 bf16.
// DOUBLE-BUFFERED LDS: stage(k+1) issued right after the barrier publishing
// stage(k); one barrier per K-iter; the vmcnt drain for k+1 sits a full
// compute phase after issue (hides staging latency; R6's 2-barrier loop
// exposed it -> MfmaUtil 7.5%).
// flags: 1 = relu, 2 = bf16 output (else fp32), 4 = accumulate BN stats
// Optional fused row-dot: dotout[row] += sum_col v[row,col]*dotv[col]
__global__ __launch_bounds__(256)
void mfma_gemm(const __hip_bfloat16* __restrict__ Abf,
               const __hip_bfloat16* __restrict__ Btbf,
               const float* __restrict__ bias, void* __restrict__ out,
               const float* __restrict__ dotv, float* __restrict__ dotout,
               float* __restrict__ stats,
               int Kp, int ldc, int Mstore, int Nstore, int flags)
{
    __shared__ __align__(16) short As[2][128 * 32];
    __shared__ __align__(16) short Bs[2][128 * 32];
    const short* A  = (const short*)Abf;
    const short* Bt = (const short*)Btbf;

    const int tid  = threadIdx.x;
    const int lane = tid & 63;
    const int wv   = tid >> 6;
    const int wr   = (wv >> 1) * 64;
    const int wc   = (wv & 1) * 64;
    const int quad = lane >> 4;
    const int l16  = lane & 15;
    const long bm = (long)blockIdx.x * 128;
    const long bn = (long)blockIdx.y * 128;

    const int r0 = tid >> 2;
    const int c0 = (tid & 3) ^ ((r0 >> 1) & 3);
    const int r1 = r0 + 64;
    const int c1 = (tid & 3) ^ ((r1 >> 1) & 3);
    const short* a_g0 = A + (bm + r0) * (long)Kp + c0 * 8;
    const short* a_g1 = A + (bm + r1) * (long)Kp + c1 * 8;
    const short* b_g0 = Bt + (bn + r0) * (long)Kp + c0 * 8;
    const short* b_g1 = Bt + (bn + r1) * (long)Kp + c1 * 8;

    f32x4 acc[4][4] = {};
    const int xr = (quad ^ ((l16 >> 1) & 3)) * 8;
    const int nIter = Kp >> 5;

    // prologue: stage iter 0 into buffer 0
    {
        gl_lds16(a_g0, &As[0][tid * 8]);
        gl_lds16(a_g1, &As[0][(tid + 256) * 8]);
        gl_lds16(b_g0, &Bs[0][tid * 8]);
        gl_lds16(b_g1, &Bs[0][(tid + 256) * 8]);
    }

    for (int it = 0; it < nIter; it++) {
        __syncthreads();               // drains stage(it); reader/writer fence
        const int nb = (it + 1) & 1;
        if (it + 1 < nIter) {          // prefetch next tile into other buffer
            const int k = (it + 1) * 32;
            gl_lds16(a_g0 + k, &As[nb][tid * 8]);
            gl_lds16(a_g1 + k, &As[nb][(tid + 256) * 8]);
            gl_lds16(b_g0 + k, &Bs[nb][tid * 8]);
            gl_lds16(b_g1 + k, &Bs[nb][(tid + 256) * 8]);
        }
        const int cb = it & 1;
        bf16x8 af[4], bf[4];
#pragma unroll
        for (int i = 0; i < 4; i++)
            af[i] = *(const bf16x8*)&As[cb][(wr + i * 16 + l16) * 32 + xr];
#pragma unroll
        for (int j = 0; j < 4; j++)
            bf[j] = *(const bf16x8*)&Bs[cb][(wc + j * 16 + l16) * 32 + xr];
#pragma unroll
        for (int i = 0; i < 4; i++)
#pragma unroll
            for (int j = 0; j < 4; j++)
                acc[i][j] = __builtin_amdgcn_mfma_f32_16x16x32_bf16(
                    af[i], bf[j], acc[i][j], 0, 0, 0);
    }

    __hip_bfloat16* outb = (__hip_bfloat16*)out;
    float* outf = (float*)out;
    float dp[16];
    float sv[4], sv2[4];
#pragma unroll
    for (int t = 0; t < 16; t++) dp[t] = 0.f;
#pragma unroll
    for (int j = 0; j < 4; j++) { sv[j] = 0.f; sv2[j] = 0.f; }

#pragma unroll
    for (int i = 0; i < 4; i++) {
        long row_base = bm + wr + i * 16 + quad * 4;
#pragma unroll
        for (int j = 0; j < 4; j++) {
            long col = bn + wc + j * 16 + l16;
            if (col >= Nstore) continue;
            float bv = bias ? bias[col] : 0.f;
            float dv = dotout ? dotv[col] : 0.f;
#pragma unroll
            for (int r = 0; r < 4; r++) {
                long row = row_base + r;
                float v = acc[i][j][r] + bv;
                if (flags & 1) v = fmaxf(v, 0.f);
                dp[i * 4 + r] = fmaf(v, dv, dp[i * 4 + r]);
                if (row >= Mstore) continue;
                if (flags & 4) { sv[j] += v; sv2[j] += v * v; }
                if (flags & 2) outb[row * ldc + col] = __float2bfloat16(v);
                else           outf[row * ldc + col] = v;
            }
        }
    }

    if (dotout) {
#pragma unroll
        for (int t = 0; t < 16; t++) {
            float s = dp[t];
            s += __shfl_xor(s, 1); s += __shfl_xor(s, 2);
            s += __shfl_xor(s, 4); s += __shfl_xor(s, 8);
            if (l16 == 0) {
                long row = bm + wr + (t >> 2) * 16 + quad * 4 + (t & 3);
                if (row < Mstore) atomicAdd(&dotout[row], s);
            }
        }
    }

    if (flags & 4) {
#pragma unroll
        for (int j = 0; j < 4; j++) {
            float s = sv[j], s2 = sv2[j];
            s  += __shfl_xor(s, 16);  s  += __shfl_xor(s, 32);
            s2 += __shfl_xor(s2, 16); s2 += __shfl_xor(s2, 32);
            if (quad == 0) {
                long col = bn + wc + j * 16 + l16;
                if (col < Nstore) {
                    atomicAdd(&stats[col], s);
                    atomicAdd(&stats[64 + col], s2);
                }
            }
        }
    }
}

// ---------------- casts ----------------
// x [NN,300] fp32 -> [MP,320] bf16 zero-padded. 8 cols/thread, 40 thr/row.
__global__ __launch_bounds__(256)
void cast_x_vec(const float* __restrict__ x, __hip_bfloat16* __restrict__ xb)
{
    const int idx = blockIdx.x * 256 + threadIdx.x;
    if (idx >= MP * 40) return;
    const int row = idx / 40;
    const int c8  = (idx % 40) * 8;
    uint4 v;
    if (row < NN && c8 + 8 <= 300) {
        const float* xp = x + (size_t)row * 300 + c8;
        float4 f0 = *(const float4*)xp;
        float4 f1 = *(const float4*)(xp + 4);
        v.x = pk2(f0.x, f0.y); v.y = pk2(f0.z, f0.w);
        v.z = pk2(f1.x, f1.y); v.w = pk2(f1.z, f1.w);
    } else {
        float f[8];
#pragma unroll
        for (int k = 0; k < 8; k++)
            f[k] = (row < NN && c8 + k < 300) ? x[(size_t)row * 300 + c8 + k] : 0.f;
        v.x = pk2(f[0], f[1]); v.y = pk2(f[2], f[3]);
        v.z = pk2(f[4], f[5]); v.w = pk2(f[6], f[7]);
    }
    *(uint4*)((ushort*)xb + (size_t)row * 320 + c8) = v;
}

// merged small-tensor prep: 4 transposed weight casts + 2 attention matvecs
__device__ inline void castT_one(const float* __restrict__ w,
                                 __hip_bfloat16* __restrict__ wt,
                                 int K, int N, int Kp, int idx)
{
    int n = idx / Kp, k = idx % Kp;
    float v = (n < N && k < K) ? w[(size_t)k * N + n] : 0.f;
    wt[idx] = __float2bfloat16(v);
}

__global__ __launch_bounds__(256)
void prep_small(const float* __restrict__ lin_w, const float* __restrict__ w1_src,
                const float* __restrict__ w2_src, const float* __restrict__ fc1_w,
                const float* __restrict__ w1_dst, const float* __restrict__ a1_dst,
                const float* __restrict__ w2_dst, const float* __restrict__ a2_dst,
                __hip_bfloat16* __restrict__ wlinT, __hip_bfloat16* __restrict__ w1T,
                __hip_bfloat16* __restrict__ w2T, __hip_bfloat16* __restrict__ fc1T,
                float* __restrict__ vvec1, float* __restrict__ vvec2)
{
    const int b = blockIdx.x;
    const int tid = threadIdx.x;
    if (b < 320) {                       // wlinT: 256x320
        castT_one(lin_w, wlinT, 300, 256, 320, b * 256 + tid);
    } else if (b < 576) {                // w1T: 256x256
        castT_one(w1_src, w1T, 256, 256, 256, (b - 320) * 256 + tid);
    } else if (b < 704) {                // w2T: 128x256
        castT_one(w2_src, w2T, 256, 128, 256, (b - 576) * 256 + tid);
    } else if (b < 768) {                // fc1T: 128x128 (N=64 real)
        castT_one(fc1_w, fc1T, 128, 64, 128, (b - 704) * 256 + tid);
    } else if (b == 768) {               // vvec1[i] = sum_j w1_dst[i,j]*a1_dst[j]
        float s = 0.f;
        for (int j = 0; j < 256; j++) s = fmaf(w1_dst[(size_t)tid * 256 + j], a1_dst[j], s);
        vvec1[tid] = s;
    } else {                             // vvec2[i] = sum_j w2_dst[i,j]*a2_dst[j]
        float s = 0.f;
        for (int j = 0; j < 128; j++) s = fmaf(w2_dst[(size_t)tid * 128 + j], a2_dst[j], s);
        vvec2[tid] = s;
    }
}

// ---------------- CSR build ----------------
__global__ void count_edges(const int* __restrict__ ei, int* __restrict__ counts)
{
    int e = blockIdx.x * blockDim.x + threadIdx.x;
    if (e >= ETOT) return;
    int d = (e < NE) ? ei[NE + e] : (e - NE);
    atomicAdd(&counts[d], 1);
}

__global__ __launch_bounds__(256)
void scan_partial(const int* __restrict__ counts, int* __restrict__ blk)
{
    __shared__ int sh[256];
    const int tid = threadIdx.x;
    const int base = blockIdx.x * SCHUNK + tid * 2;
    int c0 = (base < NN)     ? counts[base]     : 0;
    int c1 = (base + 1 < NN) ? counts[base + 1] : 0;
    sh[tid] = c0 + c1;
    __syncthreads();
    for (int off = 128; off; off >>= 1) {
        if (tid < off) sh[tid] += sh[tid + off];
        __syncthreads();
    }
    if (tid == 0) blk[blockIdx.x] = sh[0];
}

__global__ __launch_bounds__(256)
void scan_blocks(int* __restrict__ blk)
{
    __shared__ int sh[256];
    const int tid = threadIdx.x;
    int v = (tid < NBLK) ? blk[tid] : 0;
    sh[tid] = v;
    __syncthreads();
    for (int off = 1; off < 256; off <<= 1) {
        int u = (tid >= off) ? sh[tid - off] : 0;
        __syncthreads();
        sh[tid] += u;
        __syncthreads();
    }
    if (tid < NBLK) blk[tid] = sh[tid] - v;   // exclusive
}

__global__ __launch_bounds__(256)
void scan_fill(const int* __restrict__ counts, const int* __restrict__ blk,
               int* __restrict__ row_ptr, int* __restrict__ cursor)
{
    __shared__ int sh[256];
    const int tid = threadIdx.x;
    const int i0 = blockIdx.x * SCHUNK + tid * 2;
    int c0 = (i0 < NN)     ? counts[i0]     : 0;
    int c1 = (i0 + 1 < NN) ? counts[i0 + 1] : 0;
    int s = c0 + c1;
    sh[tid] = s;
    __syncthreads();
    for (int off = 1; off < 256; off <<= 1) {
        int u = (tid >= off) ? sh[tid - off] : 0;
        __syncthreads();
        sh[tid] += u;
        __syncthreads();
    }
    int pre = sh[tid] - s + blk[blockIdx.x];
    if (i0 < NN)     { row_ptr[i0] = pre;          cursor[i0] = pre; }
    if (i0 + 1 < NN) { row_ptr[i0 + 1] = pre + c0; cursor[i0 + 1] = pre + c0; }
    if (blockIdx.x == 0 && tid == 0) row_ptr[NN] = ETOT;
}

__global__ void fill_edges(const int* __restrict__ ei, int* __restrict__ cursor,
                           int* __restrict__ csr_src)
{
    int e = blockIdx.x * blockDim.x + threadIdx.x;
    if (e >= ETOT) return;
    int s, d;
    if (e < NE) { s = ei[e]; d = ei[NE + e]; }
    else        { s = e - NE; d = s; }
    int pos = atomicAdd(&cursor[d], 1);
    csr_src[pos] = s;
}

// ---------------- GAT attention + aggregation ------------------------------
// LPN lanes per node, 4 channels per lane (C = LPN*4). Softmax WITHOUT max
// subtraction (shift-invariant; e = a_s + a_d is O(1) here). (w,src) staged
// in per-wave LDS; 8 gathers in flight per iter.
template<int LPN>
__global__ __launch_bounds__(256)
void gat_agg_wave(const __hip_bfloat16* __restrict__ hsrc,
                  const float* __restrict__ a_s,
                  const float* __restrict__ a_d,
                  const int* __restrict__ row_ptr,
                  const int* __restrict__ csr_src,
                  const float* __restrict__ bias,
                  __hip_bfloat16* __restrict__ outh,
                  const float* __restrict__ dotv,
                  float* __restrict__ dotout)
{
    const int C = LPN * 4;
    const int NPB = 256 / LPN;               // nodes per block
    __shared__ __align__(16) float2 ws_sh[NPB][LPN];

    const int tid  = threadIdx.x;
    const int slot = tid / LPN;
    const int sub  = tid % LPN;
    const int n = blockIdx.x * NPB + slot;
    if (n >= NN) return;

    const int start = row_ptr[n];
    const int deg = row_ptr[n + 1] - start;
    const float a_dn = a_d[n];
    const ushort* hp = (const ushort*)hsrc;

    float S = 0.f;
    float acc0 = 0.f, acc1 = 0.f, acc2 = 0.f, acc3 = 0.f;

    for (int c0 = 0; c0 < deg; c0 += LPN) {
        const int cnt = min(LPN, deg - c0);
        int sj = 0; float w = 0.f;
        if (sub < cnt) {
            sj = csr_src[start + c0 + sub];
            float t = a_s[sj] + a_dn;
            t = (t >= 0.f) ? t : 0.2f * t;
            w = __expf(t);
        }
        S += w;
        ws_sh[slot][sub] = make_float2(w, __int_as_float(sj));

        const int cnt8 = (cnt + 7) & ~7;
        const ushort* hpl = hp + sub * 4;
        for (int j = 0; j < cnt8; j += 8) {
            float4 p0 = *(const float4*)&ws_sh[slot][j];
            float4 p1 = *(const float4*)&ws_sh[slot][j + 2];
            float4 p2 = *(const float4*)&ws_sh[slot][j + 4];
            float4 p3 = *(const float4*)&ws_sh[slot][j + 6];
            uint2 u0 = *(const uint2*)(hpl + (size_t)__float_as_int(p0.y) * C);
            uint2 u1 = *(const uint2*)(hpl + (size_t)__float_as_int(p0.w) * C);
            uint2 u2 = *(const uint2*)(hpl + (size_t)__float_as_int(p1.y) * C);
            uint2 u3 = *(const uint2*)(hpl + (size_t)__float_as_int(p1.w) * C);
            uint2 u4 = *(const uint2*)(hpl + (size_t)__float_as_int(p2.y) * C);
            uint2 u5 = *(const uint2*)(hpl + (size_t)__float_as_int(p2.w) * C);
            uint2 u6 = *(const uint2*)(hpl + (size_t)__float_as_int(p3.y) * C);
            uint2 u7 = *(const uint2*)(hpl + (size_t)__float_as_int(p3.w) * C);
#define ACC4(W, U) \
            acc0 = fmaf(W, __uint_as_float(U.x << 16), acc0); \
            acc1 = fmaf(W, __uint_as_float(U.x & 0xffff0000u), acc1); \
            acc2 = fmaf(W, __uint_as_float(U.y << 16), acc2); \
            acc3 = fmaf(W, __uint_as_float(U.y & 0xffff0000u), acc3);
            ACC4(p0.x, u0) ACC4(p0.z, u1) ACC4(p1.x, u2) ACC4(p1.z, u3)
            ACC4(p2.x, u4) ACC4(p2.z, u5) ACC4(p3.x, u6) ACC4(p3.z, u7)
#undef ACC4
        }
    }

#pragma unroll
    for (int off = LPN / 2; off; off >>= 1) S += __shfl_xor(S, off);

    float inv = 1.f / (S + 1e-16f);
    const float4 b4 = *(const float4*)&bias[sub * 4];
    float o0 = fmaxf(acc0 * inv + b4.x, 0.f);
    float o1 = fmaxf(acc1 * inv + b4.y, 0.f);
    float o2 = fmaxf(acc2 * inv + b4.z, 0.f);
    float o3 = fmaxf(acc3 * inv + b4.w, 0.f);

    ushort4 v;
    v.x = f2bf(o0); v.y = f2bf(o1); v.z = f2bf(o2); v.w = f2bf(o3);
    *(ushort4*)((ushort*)outh + (size_t)n * C + sub * 4) = v;

    if (dotout) {
        const float4 d4 = *(const float4*)&dotv[sub * 4];
        float dp = o0 * d4.x + o1 * d4.y + o2 * d4.z + o3 * d4.w;
#pragma unroll
        for (int off = LPN / 2; off; off >>= 1) dp += __shfl_xor(dp, off);
        if (sub == 0) dotout[n] = dp;
    }
}

// ---------------- BN finalize + fused head ----------------
__global__ void bn_finalize(const float* __restrict__ stats,
                            const float* __restrict__ g, const float* __restrict__ b,
                            float* __restrict__ ss)
{
    int c = threadIdx.x;
    float mu = stats[c] / (float)NN;
    float var = stats[64 + c] / (float)NN - mu * mu;
    float rs = rsqrtf(var + 1e-5f);
    float sc = rs * g[c];
    ss[c] = sc;
    ss[64 + c] = b[c] - mu * sc;
}

__global__ __launch_bounds__(256)
void final_head(const float* __restrict__ h3, const float* __restrict__ ss,
                const float* __restrict__ fc2_w, const float* __restrict__ fc2_b,
                float* __restrict__ out)
{
    int lane = threadIdx.x & 63;
    int n = blockIdx.x * 4 + (threadIdx.x >> 6);
    if (n >= NN) return;
    float y = h3[(size_t)n * 64 + lane];
    y = fmaxf(y * ss[lane] + ss[64 + lane], 0.f);
    float z[4];
#pragma unroll
    for (int o = 0; o < 4; o++) {
        float p = y * fc2_w[lane * 4 + o];
#pragma unroll
        for (int off = 32; off; off >>= 1) p += __shfl_xor(p, off);
        z[o] = p + fc2_b[o];
    }
    float mx = fmaxf(fmaxf(z[0], z[1]), fmaxf(z[2], z[3]));
    float lse = mx + logf(expf(z[0] - mx) + expf(z[1] - mx) +
                          expf(z[2] - mx) + expf(z[3] - mx));
    if (lane < 4) out[(size_t)n * 4 + lane] = z[lane] - lse;
}

// ---------------- launch ----------------
extern "C" void kernel_launch(void* const* d_in, const int* in_sizes, int n_in,
                              void* d_out, int out_size, void* d_ws, size_t ws_size,
                              hipStream_t stream)
{
    const float* x      = (const float*)d_in[0];
    const int*   ei     = (const int*)d_in[1];
    const float* lin_w  = (const float*)d_in[2];
    const float* lin_b  = (const float*)d_in[3];
    const float* w1_src = (const float*)d_in[4];
    const float* w1_dst = (const float*)d_in[5];
    const float* a1_src = (const float*)d_in[6];
    const float* a1_dst = (const float*)d_in[7];
    const float* b1     = (const float*)d_in[8];
    const float* w2_src = (const float*)d_in[9];
    const float* w2_dst = (const float*)d_in[10];
    const float* a2_src = (const float*)d_in[11];
    const float* a2_dst = (const float*)d_in[12];
    const float* b2     = (const float*)d_in[13];
    const float* fc1_w  = (const float*)d_in[14];
    const float* fc1_b  = (const float*)d_in[15];
    const float* bn_g   = (const float*)d_in[16];
    const float* bn_b   = (const float*)d_in[17];
    const float* fc2_w  = (const float*)d_in[18];
    const float* fc2_b  = (const float*)d_in[19];
    float* out = (float*)d_out;

    // -------- workspace layout (region reuse) --------
    char* p = (char*)d_ws;
    auto alloc = [&](size_t bytes) { char* r = p; p += (bytes + 255) & ~(size_t)255; return r; };
    char* R1 = alloc((size_t)MP * 320 * 2);   // x_bf  -> hsrc1
    char* R2 = alloc((size_t)MP * 256 * 2);   // h0    -> hsrc2 | h2
    char* R3 = alloc((size_t)MP * 256 * 2);   // h1    -> h3(f32)
    __hip_bfloat16* wlinT = (__hip_bfloat16*)alloc(256 * 320 * 2);
    __hip_bfloat16* w1T   = (__hip_bfloat16*)alloc(256 * 256 * 2);
    __hip_bfloat16* w2T   = (__hip_bfloat16*)alloc(128 * 256 * 2);
    __hip_bfloat16* fc1T  = (__hip_bfloat16*)alloc(128 * 128 * 2);
    float* avec  = (float*)alloc((size_t)NN * 4 * 4 + 512); // aS1|aD1|aS2|aD2|stats
    float* aS1 = avec;
    float* aD1 = avec + NN;
    float* aS2 = avec + 2 * (size_t)NN;
    float* aD2 = avec + 3 * (size_t)NN;
    float* stats = avec + 4 * (size_t)NN;     // 128 floats, zeroed with avec
    float* vvec1 = (float*)alloc(256 * 4);
    float* vvec2 = (float*)alloc(256 * 4);
    float* ss    = (float*)alloc(128 * 4);
    int* row_ptr = (int*)alloc((size_t)(NN + 1) * 4);
    int* cursor  = (int*)alloc((size_t)(NN + 1) * 4);
    int* counts  = (int*)alloc((size_t)NN * 4);
    int* blk     = (int*)alloc(256 * 4);
    int* csr_src = (int*)alloc((size_t)ETOT * 4);

    __hip_bfloat16* x_bf  = (__hip_bfloat16*)R1;
    __hip_bfloat16* hsrc1 = (__hip_bfloat16*)R1;
    __hip_bfloat16* h0    = (__hip_bfloat16*)R2;
    __hip_bfloat16* hsrc2 = (__hip_bfloat16*)R2;
    __hip_bfloat16* h2    = (__hip_bfloat16*)(R2 + (size_t)MP * 128 * 2);
    __hip_bfloat16* h1    = (__hip_bfloat16*)R3;
    float*          h3    = (float*)R3;

    const int eb = (ETOT + 255) / 256;
    const int MB = MP / 128;   // 782

    // zero atomic dot outputs + BN stats in one memset
    hipMemsetAsync(avec, 0, sizeof(float) * NN * 4 + 512, stream);

    // CSR build (parallel 3-phase scan; reused by both GAT layers)
    hipMemsetAsync(counts, 0, sizeof(int) * NN, stream);
    count_edges<<<eb, 256, 0, stream>>>(ei, counts);
    scan_partial<<<NBLK, 256, 0, stream>>>(counts, blk);
    scan_blocks<<<1, 256, 0, stream>>>(blk);
    scan_fill<<<NBLK, 256, 0, stream>>>(counts, blk, row_ptr, cursor);
    fill_edges<<<eb, 256, 0, stream>>>(ei, cursor, csr_src);

    // casts + attention weight matvecs (merged)
    cast_x_vec<<<(MP * 40 + 255) / 256, 256, 0, stream>>>(x, x_bf);
    prep_small<<<770, 256, 0, stream>>>(lin_w, w1_src, w2_src, fc1_w,
                                        w1_dst, a1_dst, w2_dst, a2_dst,
                                        wlinT, w1T, w2T, fc1T, vvec1, vvec2);

    // h0 = relu(x @ lin_w + lin_b)   [bf16 out]; fused: aD1 = h0 @ vvec1
    mfma_gemm<<<dim3(MB, 2), 256, 0, stream>>>(x_bf, wlinT, lin_b, h0,
                                               vvec1, aD1, nullptr, 320, 256, NN, 256, 3);

    // ---- GAT layer 1 (256 -> 256) ----
    mfma_gemm<<<dim3(MB, 2), 256, 0, stream>>>(h0, w1T, nullptr, hsrc1,
                                               a1_src, aS1, nullptr, 256, 256, NN, 256, 2);
    gat_agg_wave<64><<<(NN + 3) / 4, 256, 0, stream>>>(hsrc1, aS1, aD1, row_ptr,
                                                       csr_src, b1, h1, vvec2, aD2);

    // ---- GAT layer 2 (256 -> 128) ----
    mfma_gemm<<<dim3(MB, 1), 256, 0, stream>>>(h1, w2T, nullptr, hsrc2,
                                               a2_src, aS2, nullptr, 256, 128, NN, 128, 2);
    gat_agg_wave<32><<<(NN + 7) / 8, 256, 0, stream>>>(hsrc2, aS2, aD2, row_ptr,
                                                       csr_src, b2, h2, nullptr, nullptr);

    // ---- fc1 (+fused BN stats) + BN + relu + fc2 + log_softmax ----
    mfma_gemm<<<dim3(MB, 1), 256, 0, stream>>>(h2, fc1T, fc1_b, h3,
                                               nullptr, nullptr, stats, 128, 64, NN, 64, 4);
    bn_finalize<<<1, 64, 0, stream>>>(stats, bn_g, bn_b, ss);
    final_head<<<(NN + 3) / 4, 256, 0, stream>>>(h3, ss, fc2_w, fc2_b, out);
}

// Round 10
// 686.798 us; speedup vs baseline: 1.0723x; 1.0174x over previous
//
#include <hip/hip_runtime.h>
#include <hip/hip_bf16.h>
#include <cmath>

#define NN 100000
#define NE 800000
#define ETOT (NE + NN)
#define MP 100096            // 782 * 128, padded row count

#define SCHUNK 512
#define NBLK ((NN + SCHUNK - 1) / SCHUNK)   // 196

typedef __attribute__((ext_vector_type(8))) short bf16x8;
typedef __attribute__((ext_vector_type(4))) float f32x4;

__device__ inline void gl_lds16(const void* g, void* l) {
    __builtin_amdgcn_global_load_lds(
        (const __attribute__((address_space(1))) void*)g,
        (__attribute__((address_space(3))) void*)l, 16, 0, 0);
}

__device__ inline ushort f2bf(float f) {
    __hip_bfloat16 b = __float2bfloat16(f);
    return *(ushort*)&b;
}
__device__ inline uint pk2(float a, float b) {
    return (uint)f2bf(a) | ((uint)f2bf(b) << 16);
}

// ---------------- MFMA GEMM: C[M,N] = A[M,Kp] @ Bt[N,Kp]^T ------------------
// 64x128 tile (was 128x128): 32 AGPR acc/wave, 24 KB LDS/block -> 4-5 resident
// blocks/CU (vs ~1.4 at 128-tile, occupancy counter 17%). More blocks = more
// staging loads in flight = A-stream goes BW-bound instead of latency-bound.
// Double-buffered LDS, one barrier per K-iter.
// flags: 1 = relu, 2 = bf16 output (else fp32), 4 = accumulate BN stats
// Optional fused row-dot: dotout[row] += sum_col v[row,col]*dotv[col]
__global__ __launch_bounds__(256)
void mfma_gemm(const __hip_bfloat16* __restrict__ Abf,
               const __hip_bfloat16* __restrict__ Btbf,
               const float* __restrict__ bias, void* __restrict__ out,
               const float* __restrict__ dotv, float* __restrict__ dotout,
               float* __restrict__ stats,
               int Kp, int ldc, int Mstore, int Nstore, int flags)
{
    __shared__ __align__(16) short As[2][64 * 32];    // 4 KB per buffer
    __shared__ __align__(16) short Bs[2][128 * 32];   // 8 KB per buffer
    const short* A  = (const short*)Abf;
    const short* Bt = (const short*)Btbf;

    const int tid  = threadIdx.x;
    const int lane = tid & 63;
    const int wv   = tid >> 6;
    const int wr   = (wv >> 1) * 32;
    const int wc   = (wv & 1) * 64;
    const int quad = lane >> 4;
    const int l16  = lane & 15;
    const long bm = (long)blockIdx.x * 64;
    const long bn = (long)blockIdx.y * 128;

    // A staging: 64 rows x 32 K = 256 x 16B chunks, 1 per thread
    const int ar = tid >> 2;
    const int ac = (tid & 3) ^ ((ar >> 1) & 3);
    const short* a_g = A + (bm + ar) * (long)Kp + ac * 8;
    // B staging: 128 rows x 32 K = 512 chunks, 2 per thread
    const int r0 = tid >> 2;
    const int c0 = (tid & 3) ^ ((r0 >> 1) & 3);
    const int r1 = r0 + 64;
    const int c1 = (tid & 3) ^ ((r1 >> 1) & 3);
    const short* b_g0 = Bt + (bn + r0) * (long)Kp + c0 * 8;
    const short* b_g1 = Bt + (bn + r1) * (long)Kp + c1 * 8;

    f32x4 acc[2][4] = {};
    const int xr = (quad ^ ((l16 >> 1) & 3)) * 8;
    const int nIter = Kp >> 5;

    // prologue: stage iter 0 into buffer 0
    gl_lds16(a_g, &As[0][tid * 8]);
    gl_lds16(b_g0, &Bs[0][tid * 8]);
    gl_lds16(b_g1, &Bs[0][(tid + 256) * 8]);

    for (int it = 0; it < nIter; it++) {
        __syncthreads();               // drains stage(it); reader/writer fence
        const int nb = (it + 1) & 1;
        if (it + 1 < nIter) {          // prefetch next tile into other buffer
            const int k = (it + 1) * 32;
            gl_lds16(a_g + k, &As[nb][tid * 8]);
            gl_lds16(b_g0 + k, &Bs[nb][tid * 8]);
            gl_lds16(b_g1 + k, &Bs[nb][(tid + 256) * 8]);
        }
        const int cb = it & 1;
        bf16x8 af[2], bf[4];
#pragma unroll
        for (int i = 0; i < 2; i++)
            af[i] = *(const bf16x8*)&As[cb][(wr + i * 16 + l16) * 32 + xr];
#pragma unroll
        for (int j = 0; j < 4; j++)
            bf[j] = *(const bf16x8*)&Bs[cb][(wc + j * 16 + l16) * 32 + xr];
#pragma unroll
        for (int i = 0; i < 2; i++)
#pragma unroll
            for (int j = 0; j < 4; j++)
                acc[i][j] = __builtin_amdgcn_mfma_f32_16x16x32_bf16(
                    af[i], bf[j], acc[i][j], 0, 0, 0);
    }

    __hip_bfloat16* outb = (__hip_bfloat16*)out;
    float* outf = (float*)out;
    float dp[8];
    float sv[4], sv2[4];
#pragma unroll
    for (int t = 0; t < 8; t++) dp[t] = 0.f;
#pragma unroll
    for (int j = 0; j < 4; j++) { sv[j] = 0.f; sv2[j] = 0.f; }

#pragma unroll
    for (int i = 0; i < 2; i++) {
        long row_base = bm + wr + i * 16 + quad * 4;
#pragma unroll
        for (int j = 0; j < 4; j++) {
            long col = bn + wc + j * 16 + l16;
            if (col >= Nstore) continue;
            float bv = bias ? bias[col] : 0.f;
            float dv = dotout ? dotv[col] : 0.f;
#pragma unroll
            for (int r = 0; r < 4; r++) {
                long row = row_base + r;
                float v = acc[i][j][r] + bv;
                if (flags & 1) v = fmaxf(v, 0.f);
                dp[i * 4 + r] = fmaf(v, dv, dp[i * 4 + r]);
                if (row >= Mstore) continue;
                if (flags & 4) { sv[j] += v; sv2[j] += v * v; }
                if (flags & 2) outb[row * ldc + col] = __float2bfloat16(v);
                else           outf[row * ldc + col] = v;
            }
        }
    }

    if (dotout) {
#pragma unroll
        for (int t = 0; t < 8; t++) {
            float s = dp[t];
            s += __shfl_xor(s, 1); s += __shfl_xor(s, 2);
            s += __shfl_xor(s, 4); s += __shfl_xor(s, 8);
            if (l16 == 0) {
                long row = bm + wr + (t >> 2) * 16 + quad * 4 + (t & 3);
                if (row < Mstore) atomicAdd(&dotout[row], s);
            }
        }
    }

    if (flags & 4) {
#pragma unroll
        for (int j = 0; j < 4; j++) {
            float s = sv[j], s2 = sv2[j];
            s  += __shfl_xor(s, 16);  s  += __shfl_xor(s, 32);
            s2 += __shfl_xor(s2, 16); s2 += __shfl_xor(s2, 32);
            if (quad == 0) {
                long col = bn + wc + j * 16 + l16;
                if (col < Nstore) {
                    atomicAdd(&stats[col], s);
                    atomicAdd(&stats[64 + col], s2);
                }
            }
        }
    }
}

// ---------------- casts ----------------
// x [NN,300] fp32 -> [MP,320] bf16 zero-padded. 8 cols/thread, 40 thr/row.
__global__ __launch_bounds__(256)
void cast_x_vec(const float* __restrict__ x, __hip_bfloat16* __restrict__ xb)
{
    const int idx = blockIdx.x * 256 + threadIdx.x;
    if (idx >= MP * 40) return;
    const int row = idx / 40;
    const int c8  = (idx % 40) * 8;
    uint4 v;
    if (row < NN && c8 + 8 <= 300) {
        const float* xp = x + (size_t)row * 300 + c8;
        float4 f0 = *(const float4*)xp;
        float4 f1 = *(const float4*)(xp + 4);
        v.x = pk2(f0.x, f0.y); v.y = pk2(f0.z, f0.w);
        v.z = pk2(f1.x, f1.y); v.w = pk2(f1.z, f1.w);
    } else {
        float f[8];
#pragma unroll
        for (int k = 0; k < 8; k++)
            f[k] = (row < NN && c8 + k < 300) ? x[(size_t)row * 300 + c8 + k] : 0.f;
        v.x = pk2(f[0], f[1]); v.y = pk2(f[2], f[3]);
        v.z = pk2(f[4], f[5]); v.w = pk2(f[6], f[7]);
    }
    *(uint4*)((ushort*)xb + (size_t)row * 320 + c8) = v;
}

// merged small-tensor prep: 4 transposed weight casts + 2 attention matvecs
__device__ inline void castT_one(const float* __restrict__ w,
                                 __hip_bfloat16* __restrict__ wt,
                                 int K, int N, int Kp, int idx)
{
    int n = idx / Kp, k = idx % Kp;
    float v = (n < N && k < K) ? w[(size_t)k * N + n] : 0.f;
    wt[idx] = __float2bfloat16(v);
}

__global__ __launch_bounds__(256)
void prep_small(const float* __restrict__ lin_w, const float* __restrict__ w1_src,
                const float* __restrict__ w2_src, const float* __restrict__ fc1_w,
                const float* __restrict__ w1_dst, const float* __restrict__ a1_dst,
                const float* __restrict__ w2_dst, const float* __restrict__ a2_dst,
                __hip_bfloat16* __restrict__ wlinT, __hip_bfloat16* __restrict__ w1T,
                __hip_bfloat16* __restrict__ w2T, __hip_bfloat16* __restrict__ fc1T,
                float* __restrict__ vvec1, float* __restrict__ vvec2)
{
    const int b = blockIdx.x;
    const int tid = threadIdx.x;
    if (b < 320) {                       // wlinT: 256x320
        castT_one(lin_w, wlinT, 300, 256, 320, b * 256 + tid);
    } else if (b < 576) {                // w1T: 256x256
        castT_one(w1_src, w1T, 256, 256, 256, (b - 320) * 256 + tid);
    } else if (b < 704) {                // w2T: 128x256
        castT_one(w2_src, w2T, 256, 128, 256, (b - 576) * 256 + tid);
    } else if (b < 768) {                // fc1T: 128x128 (N=64 real)
        castT_one(fc1_w, fc1T, 128, 64, 128, (b - 704) * 256 + tid);
    } else if (b == 768) {               // vvec1[i] = sum_j w1_dst[i,j]*a1_dst[j]
        float s = 0.f;
        for (int j = 0; j < 256; j++) s = fmaf(w1_dst[(size_t)tid * 256 + j], a1_dst[j], s);
        vvec1[tid] = s;
    } else {                             // vvec2[i] = sum_j w2_dst[i,j]*a2_dst[j]
        float s = 0.f;
        for (int j = 0; j < 128; j++) s = fmaf(w2_dst[(size_t)tid * 128 + j], a2_dst[j], s);
        vvec2[tid] = s;
    }
}

// ---------------- CSR build ----------------
__global__ void count_edges(const int* __restrict__ ei, int* __restrict__ counts)
{
    int e = blockIdx.x * blockDim.x + threadIdx.x;
    if (e >= ETOT) return;
    int d = (e < NE) ? ei[NE + e] : (e - NE);
    atomicAdd(&counts[d], 1);
}

__global__ __launch_bounds__(256)
void scan_partial(const int* __restrict__ counts, int* __restrict__ blk)
{
    __shared__ int sh[256];
    const int tid = threadIdx.x;
    const int base = blockIdx.x * SCHUNK + tid * 2;
    int c0 = (base < NN)     ? counts[base]     : 0;
    int c1 = (base + 1 < NN) ? counts[base + 1] : 0;
    sh[tid] = c0 + c1;
    __syncthreads();
    for (int off = 128; off; off >>= 1) {
        if (tid < off) sh[tid] += sh[tid + off];
        __syncthreads();
    }
    if (tid == 0) blk[blockIdx.x] = sh[0];
}

__global__ __launch_bounds__(256)
void scan_blocks(int* __restrict__ blk)
{
    __shared__ int sh[256];
    const int tid = threadIdx.x;
    int v = (tid < NBLK) ? blk[tid] : 0;
    sh[tid] = v;
    __syncthreads();
    for (int off = 1; off < 256; off <<= 1) {
        int u = (tid >= off) ? sh[tid - off] : 0;
        __syncthreads();
        sh[tid] += u;
        __syncthreads();
    }
    if (tid < NBLK) blk[tid] = sh[tid] - v;   // exclusive
}

__global__ __launch_bounds__(256)
void scan_fill(const int* __restrict__ counts, const int* __restrict__ blk,
               int* __restrict__ row_ptr, int* __restrict__ cursor)
{
    __shared__ int sh[256];
    const int tid = threadIdx.x;
    const int i0 = blockIdx.x * SCHUNK + tid * 2;
    int c0 = (i0 < NN)     ? counts[i0]     : 0;
    int c1 = (i0 + 1 < NN) ? counts[i0 + 1] : 0;
    int s = c0 + c1;
    sh[tid] = s;
    __syncthreads();
    for (int off = 1; off < 256; off <<= 1) {
        int u = (tid >= off) ? sh[tid - off] : 0;
        __syncthreads();
        sh[tid] += u;
        __syncthreads();
    }
    int pre = sh[tid] - s + blk[blockIdx.x];
    if (i0 < NN)     { row_ptr[i0] = pre;          cursor[i0] = pre; }
    if (i0 + 1 < NN) { row_ptr[i0 + 1] = pre + c0; cursor[i0 + 1] = pre + c0; }
    if (blockIdx.x == 0 && tid == 0) row_ptr[NN] = ETOT;
}

__global__ void fill_edges(const int* __restrict__ ei, int* __restrict__ cursor,
                           int* __restrict__ csr_src)
{
    int e = blockIdx.x * blockDim.x + threadIdx.x;
    if (e >= ETOT) return;
    int s, d;
    if (e < NE) { s = ei[e]; d = ei[NE + e]; }
    else        { s = e - NE; d = s; }
    int pos = atomicAdd(&cursor[d], 1);
    csr_src[pos] = s;
}

// ---------------- GAT attention + aggregation ------------------------------
// LPN lanes per node, 4 channels per lane (C = LPN*4). Softmax WITHOUT max
// subtraction (shift-invariant; e = a_s + a_d is O(1) here). (w,src) staged
// in per-wave LDS; 8 gathers in flight per iter.
template<int LPN>
__global__ __launch_bounds__(256)
void gat_agg_wave(const __hip_bfloat16* __restrict__ hsrc,
                  const float* __restrict__ a_s,
                  const float* __restrict__ a_d,
                  const int* __restrict__ row_ptr,
                  const int* __restrict__ csr_src,
                  const float* __restrict__ bias,
                  __hip_bfloat16* __restrict__ outh,
                  const float* __restrict__ dotv,
                  float* __restrict__ dotout)
{
    const int C = LPN * 4;
    const int NPB = 256 / LPN;               // nodes per block
    __shared__ __align__(16) float2 ws_sh[NPB][LPN];

    const int tid  = threadIdx.x;
    const int slot = tid / LPN;
    const int sub  = tid % LPN;
    const int n = blockIdx.x * NPB + slot;
    if (n >= NN) return;

    const int start = row_ptr[n];
    const int deg = row_ptr[n + 1] - start;
    const float a_dn = a_d[n];
    const ushort* hp = (const ushort*)hsrc;

    float S = 0.f;
    float acc0 = 0.f, acc1 = 0.f, acc2 = 0.f, acc3 = 0.f;

    for (int c0 = 0; c0 < deg; c0 += LPN) {
        const int cnt = min(LPN, deg - c0);
        int sj = 0; float w = 0.f;
        if (sub < cnt) {
            sj = csr_src[start + c0 + sub];
            float t = a_s[sj] + a_dn;
            t = (t >= 0.f) ? t : 0.2f * t;
            w = __expf(t);
        }
        S += w;
        ws_sh[slot][sub] = make_float2(w, __int_as_float(sj));

        const int cnt8 = (cnt + 7) & ~7;
        const ushort* hpl = hp + sub * 4;
        for (int j = 0; j < cnt8; j += 8) {
            float4 p0 = *(const float4*)&ws_sh[slot][j];
            float4 p1 = *(const float4*)&ws_sh[slot][j + 2];
            float4 p2 = *(const float4*)&ws_sh[slot][j + 4];
            float4 p3 = *(const float4*)&ws_sh[slot][j + 6];
            uint2 u0 = *(const uint2*)(hpl + (size_t)__float_as_int(p0.y) * C);
            uint2 u1 = *(const uint2*)(hpl + (size_t)__float_as_int(p0.w) * C);
            uint2 u2 = *(const uint2*)(hpl + (size_t)__float_as_int(p1.y) * C);
            uint2 u3 = *(const uint2*)(hpl + (size_t)__float_as_int(p1.w) * C);
            uint2 u4 = *(const uint2*)(hpl + (size_t)__float_as_int(p2.y) * C);
            uint2 u5 = *(const uint2*)(hpl + (size_t)__float_as_int(p2.w) * C);
            uint2 u6 = *(const uint2*)(hpl + (size_t)__float_as_int(p3.y) * C);
            uint2 u7 = *(const uint2*)(hpl + (size_t)__float_as_int(p3.w) * C);
#define ACC4(W, U) \
            acc0 = fmaf(W, __uint_as_float(U.x << 16), acc0); \
            acc1 = fmaf(W, __uint_as_float(U.x & 0xffff0000u), acc1); \
            acc2 = fmaf(W, __uint_as_float(U.y << 16), acc2); \
            acc3 = fmaf(W, __uint_as_float(U.y & 0xffff0000u), acc3);
            ACC4(p0.x, u0) ACC4(p0.z, u1) ACC4(p1.x, u2) ACC4(p1.z, u3)
            ACC4(p2.x, u4) ACC4(p2.z, u5) ACC4(p3.x, u6) ACC4(p3.z, u7)
#undef ACC4
        }
    }

#pragma unroll
    for (int off = LPN / 2; off; off >>= 1) S += __shfl_xor(S, off);

    float inv = 1.f / (S + 1e-16f);
    const float4 b4 = *(const float4*)&bias[sub * 4];
    float o0 = fmaxf(acc0 * inv + b4.x, 0.f);
    float o1 = fmaxf(acc1 * inv + b4.y, 0.f);
    float o2 = fmaxf(acc2 * inv + b4.z, 0.f);
    float o3 = fmaxf(acc3 * inv + b4.w, 0.f);

    ushort4 v;
    v.x = f2bf(o0); v.y = f2bf(o1); v.z = f2bf(o2); v.w = f2bf(o3);
    *(ushort4*)((ushort*)outh + (size_t)n * C + sub * 4) = v;

    if (dotout) {
        const float4 d4 = *(const float4*)&dotv[sub * 4];
        float dp = o0 * d4.x + o1 * d4.y + o2 * d4.z + o3 * d4.w;
#pragma unroll
        for (int off = LPN / 2; off; off >>= 1) dp += __shfl_xor(dp, off);
        if (sub == 0) dotout[n] = dp;
    }
}

// ---------------- BN finalize + fused head ----------------
__global__ void bn_finalize(const float* __restrict__ stats,
                            const float* __restrict__ g, const float* __restrict__ b,
                            float* __restrict__ ss)
{
    int c = threadIdx.x;
    float mu = stats[c] / (float)NN;
    float var = stats[64 + c] / (float)NN - mu * mu;
    float rs = rsqrtf(var + 1e-5f);
    float sc = rs * g[c];
    ss[c] = sc;
    ss[64 + c] = b[c] - mu * sc;
}

__global__ __launch_bounds__(256)
void final_head(const float* __restrict__ h3, const float* __restrict__ ss,
                const float* __restrict__ fc2_w, const float* __restrict__ fc2_b,
                float* __restrict__ out)
{
    int lane = threadIdx.x & 63;
    int n = blockIdx.x * 4 + (threadIdx.x >> 6);
    if (n >= NN) return;
    float y = h3[(size_t)n * 64 + lane];
    y = fmaxf(y * ss[lane] + ss[64 + lane], 0.f);
    float z[4];
#pragma unroll
    for (int o = 0; o < 4; o++) {
        float p = y * fc2_w[lane * 4 + o];
#pragma unroll
        for (int off = 32; off; off >>= 1) p += __shfl_xor(p, off);
        z[o] = p + fc2_b[o];
    }
    float mx = fmaxf(fmaxf(z[0], z[1]), fmaxf(z[2], z[3]));
    float lse = mx + logf(expf(z[0] - mx) + expf(z[1] - mx) +
                          expf(z[2] - mx) + expf(z[3] - mx));
    if (lane < 4) out[(size_t)n * 4 + lane] = z[lane] - lse;
}

// ---------------- launch ----------------
extern "C" void kernel_launch(void* const* d_in, const int* in_sizes, int n_in,
                              void* d_out, int out_size, void* d_ws, size_t ws_size,
                              hipStream_t stream)
{
    const float* x      = (const float*)d_in[0];
    const int*   ei     = (const int*)d_in[1];
    const float* lin_w  = (const float*)d_in[2];
    const float* lin_b  = (const float*)d_in[3];
    const float* w1_src = (const float*)d_in[4];
    const float* w1_dst = (const float*)d_in[5];
    const float* a1_src = (const float*)d_in[6];
    const float* a1_dst = (const float*)d_in[7];
    const float* b1     = (const float*)d_in[8];
    const float* w2_src = (const float*)d_in[9];
    const float* w2_dst = (const float*)d_in[10];
    const float* a2_src = (const float*)d_in[11];
    const float* a2_dst = (const float*)d_in[12];
    const float* b2     = (const float*)d_in[13];
    const float* fc1_w  = (const float*)d_in[14];
    const float* fc1_b  = (const float*)d_in[15];
    const float* bn_g   = (const float*)d_in[16];
    const float* bn_b   = (const float*)d_in[17];
    const float* fc2_w  = (const float*)d_in[18];
    const float* fc2_b  = (const float*)d_in[19];
    float* out = (float*)d_out;

    // -------- workspace layout (region reuse) --------
    char* p = (char*)d_ws;
    auto alloc = [&](size_t bytes) { char* r = p; p += (bytes + 255) & ~(size_t)255; return r; };
    char* R1 = alloc((size_t)MP * 320 * 2);   // x_bf  -> hsrc1
    char* R2 = alloc((size_t)MP * 256 * 2);   // h0    -> hsrc2 | h2
    char* R3 = alloc((size_t)MP * 256 * 2);   // h1    -> h3(f32)
    __hip_bfloat16* wlinT = (__hip_bfloat16*)alloc(256 * 320 * 2);
    __hip_bfloat16* w1T   = (__hip_bfloat16*)alloc(256 * 256 * 2);
    __hip_bfloat16* w2T   = (__hip_bfloat16*)alloc(128 * 256 * 2);
    __hip_bfloat16* fc1T  = (__hip_bfloat16*)alloc(128 * 128 * 2);
    float* avec  = (float*)alloc((size_t)NN * 4 * 4 + 512); // aS1|aD1|aS2|aD2|stats
    float* aS1 = avec;
    float* aD1 = avec + NN;
    float* aS2 = avec + 2 * (size_t)NN;
    float* aD2 = avec + 3 * (size_t)NN;
    float* stats = avec + 4 * (size_t)NN;     // 128 floats, zeroed with avec
    float* vvec1 = (float*)alloc(256 * 4);
    float* vvec2 = (float*)alloc(256 * 4);
    float* ss    = (float*)alloc(128 * 4);
    int* row_ptr = (int*)alloc((size_t)(NN + 1) * 4);
    int* cursor  = (int*)alloc((size_t)(NN + 1) * 4);
    int* counts  = (int*)alloc((size_t)NN * 4);
    int* blk     = (int*)alloc(256 * 4);
    int* csr_src = (int*)alloc((size_t)ETOT * 4);

    __hip_bfloat16* x_bf  = (__hip_bfloat16*)R1;
    __hip_bfloat16* hsrc1 = (__hip_bfloat16*)R1;
    __hip_bfloat16* h0    = (__hip_bfloat16*)R2;
    __hip_bfloat16* hsrc2 = (__hip_bfloat16*)R2;
    __hip_bfloat16* h2    = (__hip_bfloat16*)(R2 + (size_t)MP * 128 * 2);
    __hip_bfloat16* h1    = (__hip_bfloat16*)R3;
    float*          h3    = (float*)R3;

    const int eb = (ETOT + 255) / 256;
    const int MB64 = MP / 64;   // 1564

    // zero atomic dot outputs + BN stats in one memset
    hipMemsetAsync(avec, 0, sizeof(float) * NN * 4 + 512, stream);

    // CSR build (parallel 3-phase scan; reused by both GAT layers)
    hipMemsetAsync(counts, 0, sizeof(int) * NN, stream);
    count_edges<<<eb, 256, 0, stream>>>(ei, counts);
    scan_partial<<<NBLK, 256, 0, stream>>>(counts, blk);
    scan_blocks<<<1, 256, 0, stream>>>(blk);
    scan_fill<<<NBLK, 256, 0, stream>>>(counts, blk, row_ptr, cursor);
    fill_edges<<<eb, 256, 0, stream>>>(ei, cursor, csr_src);

    // casts + attention weight matvecs (merged)
    cast_x_vec<<<(MP * 40 + 255) / 256, 256, 0, stream>>>(x, x_bf);
    prep_small<<<770, 256, 0, stream>>>(lin_w, w1_src, w2_src, fc1_w,
                                        w1_dst, a1_dst, w2_dst, a2_dst,
                                        wlinT, w1T, w2T, fc1T, vvec1, vvec2);

    // h0 = relu(x @ lin_w + lin_b)   [bf16 out]; fused: aD1 = h0 @ vvec1
    mfma_gemm<<<dim3(MB64, 2), 256, 0, stream>>>(x_bf, wlinT, lin_b, h0,
                                                 vvec1, aD1, nullptr, 320, 256, NN, 256, 3);

    // ---- GAT layer 1 (256 -> 256) ----
    mfma_gemm<<<dim3(MB64, 2), 256, 0, stream>>>(h0, w1T, nullptr, hsrc1,
                                                 a1_src, aS1, nullptr, 256, 256, NN, 256, 2);
    gat_agg_wave<64><<<(NN + 3) / 4, 256, 0, stream>>>(hsrc1, aS1, aD1, row_ptr,
                                                       csr_src, b1, h1, vvec2, aD2);

    // ---- GAT layer 2 (256 -> 128) ----
    mfma_gemm<<<dim3(MB64, 1), 256, 0, stream>>>(h1, w2T, nullptr, hsrc2,
                                                 a2_src, aS2, nullptr, 256, 128, NN, 128, 2);
    gat_agg_wave<32><<<(NN + 7) / 8, 256, 0, stream>>>(hsrc2, aS2, aD2, row_ptr,
                                                       csr_src, b2, h2, nullptr, nullptr);

    // ---- fc1 (+fused BN stats) + BN + relu + fc2 + log_softmax ----
    mfma_gemm<<<dim3(MB64, 1), 256, 0, stream>>>(h2, fc1T, fc1_b, h3,
                                                 nullptr, nullptr, stats, 128, 64, NN, 64, 4);
    bn_finalize<<<1, 64, 0, stream>>>(stats, bn_g, bn_b, ss);
    final_head<<<(NN + 3) / 4, 256, 0, stream>>>(h3, ss, fc2_w, fc2_b, out);
}